// Round 9
// baseline (1836.799 us; speedup 1.0000x reference)
//
#include <hip/hip_runtime.h>

typedef unsigned short u16;
typedef unsigned int   u32;

using f32x4  = __attribute__((ext_vector_type(4))) float;
using bf16x8 = __attribute__((ext_vector_type(8))) __bf16;

// ---------- helpers ----------
// native cast: clang lowers fptrunc f32->bf16 on gfx950 to v_cvt_pk_bf16_f32 (RNE)
__device__ inline u16 f2bf(float f) {
  return __builtin_bit_cast(u16, (__bf16)f);
}
__device__ inline float bf2f(u16 v) {
  u32 u = ((u32)v) << 16;
  return __builtin_bit_cast(float, u);
}
// packed f32x2 -> bf16x2 (RNE), lo = a, hi = b
__device__ inline u32 pk_bf16(float a, float b) {
  u32 d;
  asm("v_cvt_pk_bf16_f32 %0, %1, %2" : "=v"(d) : "v"(a), "v"(b));
  return d;
}

// async global->LDS, 16B per lane; LDS dst is wave-uniform base + lane*16,
// global src is PER-LANE (enables permuted-row staging, see gemm_vt).
__device__ inline void gl_lds16(const u16* g, u16* l) {
  __builtin_amdgcn_global_load_lds((const __attribute__((address_space(1))) void*)g,
                                   (__attribute__((address_space(3))) void*)l,
                                   16, 0, 0);
}

// Geometry: B=8, H=W=128, NW=8, win=16x16 (N=256), D=256, shift=8. Chunk-local.
__device__ inline int perm_fwd(int m) {
  int b = m >> 14, rem = m & 16383;
  int h = rem >> 7, w = rem & 127;
  int hr = (h - 8) & 127, wr = (w - 8) & 127;
  int win = (b << 6) | ((hr >> 4) << 3) | (wr >> 4);
  return (win << 8) | ((hr & 15) << 4) | (wr & 15);
}
__device__ inline int perm_inv(int r) {
  int win = r >> 8, t = r & 255;
  int b = win >> 6, wy = (win >> 3) & 7, wx = win & 7;
  int h = (((wy << 4) | (t >> 4)) + 8) & 127;
  int w = (((wx << 4) | (t & 15)) + 8) & 127;
  return (b << 14) | (h << 7) | w;
}

// ---------- BK=32 double-buffered staging, constant LDS ----------
// R3 lesson: dbuf at BK=64 doubled LDS -> occupancy 30->21% -> regressed.
// This version: 2 buffers of BK=32 = SAME total LDS as 1 buffer of BK=64,
// so occupancy is untouched while each barrier's vmcnt(0) drains loads that
// were issued one full compute phase earlier (latency hidden, not exposed).
// BK=32 tile: rows of 32 elems (64B = 4 chunks of 16B).
// XOR swizzle (proven 0-conflict in R0/R1): slot s of row r holds data chunk
// s ^ ((r>>1)&3). Staging lane math: row-in-16 = l>>2, slot = l&3,
// data chunk = (l&3)^((l>>3)&3). Row offsets that are multiples of 8 leave
// (r>>1)&3 invariant, so one cd works for all staged row groups.
// Fragment read: lane quad wants chunk=quad of row R -> sw = (quad^((l15>>1)&3))<<3.

enum { MODE_QKV = 0, MODE_PV = 2, MODE_FFN1 = 4 };

template<int MODE>
__global__ __launch_bounds__(256)
void gemm_nt(const u16* __restrict__ A, int lda, long long sAz,
             const u16* __restrict__ Bt, int ldb, long long sBz,
             u16* __restrict__ OutB, float* __restrict__ OutF,
             const float* __restrict__ mask, int K, int ldo)
{
  __shared__ __align__(16) u16 sA[2][128 * 32];
  __shared__ __align__(16) u16 sB[2][128 * 32];

  const int tid  = threadIdx.x;
  const int lane = tid & 63;
  const int wave = tid >> 6;
  const int l15  = lane & 15;
  const int quad = lane >> 4;
  const int wm   = (wave >> 1) << 6;
  const int wn   = (wave & 1) << 6;
  const int z    = blockIdx.z;
  const int m0   = (int)(blockIdx.y) << 7;
  const int n0   = (int)(blockIdx.x) << 7;

  const u16* Ab = A  + (long long)z * sAz;
  const u16* Bb = Bt + (long long)z * sBz;

  // staging: wave w stages rows [32w, 32w+32): 2 insts per matrix (16 rows each)
  const int cd = ((lane & 3) ^ ((lane >> 3) & 3)) << 3;   // elems
  const int rs = (wave << 5) + (lane >> 2);
  const u16* ga0 = Ab + (long long)(m0 + rs) * lda + cd;
  const u16* ga1 = ga0 + 16ll * lda;
  const u16* gb0 = Bb + (long long)(n0 + rs) * ldb + cd;
  const u16* gb1 = gb0 + 16ll * ldb;
  const int lofs = wave << 10;

  const int sw = ((((l15 >> 1) & 3) ^ quad) << 3);

  const f32x4 zero = {0.f, 0.f, 0.f, 0.f};
  f32x4 acc[4][4];
#pragma unroll
  for (int i = 0; i < 4; ++i)
#pragma unroll
    for (int j = 0; j < 4; ++j) acc[i][j] = zero;

  // prologue: stage k=0 into buf 0
  gl_lds16(ga0, &sA[0][lofs]);
  gl_lds16(ga1, &sA[0][lofs] + 512);
  gl_lds16(gb0, &sB[0][lofs]);
  gl_lds16(gb1, &sB[0][lofs] + 512);
  __syncthreads();

  int cur = 0;
  for (int k0 = 0; k0 < K; k0 += 32) {
    // issue next-tile loads first: they fly under the compute below and are
    // drained by the end-of-iter barrier's vmcnt(0) (one compute phase later)
    if (k0 + 32 < K) {
      const int nxt = cur ^ 1;
      gl_lds16(ga0 + k0 + 32, &sA[nxt][lofs]);
      gl_lds16(ga1 + k0 + 32, &sA[nxt][lofs] + 512);
      gl_lds16(gb0 + k0 + 32, &sB[nxt][lofs]);
      gl_lds16(gb1 + k0 + 32, &sB[nxt][lofs] + 512);
    }
    bf16x8 af[4], bfr[4];
#pragma unroll
    for (int i = 0; i < 4; ++i) {
      af[i]  = *(const bf16x8*)(&sA[cur][0] + ((wm + (i << 4) + l15) << 5) + sw);
      bfr[i] = *(const bf16x8*)(&sB[cur][0] + ((wn + (i << 4) + l15) << 5) + sw);
    }
#pragma unroll
    for (int i = 0; i < 4; ++i)
#pragma unroll
      for (int j = 0; j < 4; ++j)
        acc[i][j] = __builtin_amdgcn_mfma_f32_16x16x32_bf16(af[i], bfr[j], acc[i][j], 0, 0, 0);
    __syncthreads();
    cur ^= 1;
  }

  // epilogue: D[row=quad*4+r][col=l15]
#pragma unroll
  for (int i = 0; i < 4; ++i) {
#pragma unroll
    for (int r = 0; r < 4; ++r) {
      int mg = m0 + wm + (i << 4) + (quad << 2) + r;
      if constexpr (MODE == MODE_QKV) {
        // ldo = stride (elems) between stacked output buffers; block-uniform
        // buffer select by n0>>8 (merged q|k weight: rows 0:256 -> buf0,
        // 256:512 -> buf1). For N=256 grids n0>>8==0 -> plain single-buffer.
        u16* orow = OutB + (long long)(n0 >> 8) * ldo + ((long long)perm_fwd(mg) << 8);
#pragma unroll
        for (int j = 0; j < 4; ++j) {
          int ng = n0 + wn + (j << 4) + l15;
          orow[ng & 255] = f2bf(acc[i][j][r]);
        }
      } else if constexpr (MODE == MODE_PV) {
        u16* orow = OutB + ((long long)perm_inv((z << 8) + mg) << 8);
#pragma unroll
        for (int j = 0; j < 4; ++j) {
          int ng = n0 + wn + (j << 4) + l15;
          orow[ng] = f2bf(acc[i][j][r]);
        }
      } else { // MODE_FFN1: tanh-approx gelu -> bf16, SIGMA-PACKED cols, ld = ldo
        // gelu(v) ~= v * sigmoid(1.5957691216*v + 0.071354816*v^3)
        // Storage col within each 64-col group = l15*4 + j (true feature
        // f = (pos&3)<<4 | pos>>2); consumer's w2t is built with the same
        // sigma so k-pairing is preserved. Per-thread 4 contiguous cols ->
        // 2x cvt_pk + one dwordx2 store (was 4 cvt + 4 scalar stores).
        float gv[4];
#pragma unroll
        for (int j = 0; j < 4; ++j) {
          float v = acc[i][j][r];
          float t = v * fmaf(v * v, -0.071354816f, -1.5957691216f);
          gv[j] = v * __builtin_amdgcn_rcpf(1.0f + __expf(t));
        }
        uint2 d;
        d.x = pk_bf16(gv[0], gv[1]);
        d.y = pk_bf16(gv[2], gv[3]);
        *(uint2*)(OutB + (long long)mg * ldo + n0 + wn + (l15 << 2)) = d;
      }
    }
  }
}

// ---------- direct per-window V^T GEMM ----------
// vt[z][d][t] = sum_k wvt[d][k] * feat[perm_inv(z*256+t)][k].
// B-staging exploits gl_lds16's PER-LANE global source: each lane loads from
// the permuted feat row while the LDS dest stays linear.
__global__ __launch_bounds__(256)
void gemm_vt(const u16* __restrict__ Wt,    // [256][256] bf16 = wv^T (L2-hot)
             const u16* __restrict__ Feat,  // [Mc][256] bf16 unpermuted
             u16* __restrict__ Vt)          // [Wc][256][256]
{
  __shared__ __align__(16) u16 sA[2][128 * 32];
  __shared__ __align__(16) u16 sB[2][128 * 32];

  const int tid  = threadIdx.x;
  const int lane = tid & 63;
  const int wave = tid >> 6;
  const int l15  = lane & 15;
  const int quad = lane >> 4;
  const int wm   = (wave >> 1) << 6;
  const int wn   = (wave & 1) << 6;
  const int z    = blockIdx.z;
  const int m0   = (int)(blockIdx.y) << 7;   // d-tile
  const int n0   = (int)(blockIdx.x) << 7;   // t-tile

  const int cd = ((lane & 3) ^ ((lane >> 3) & 3)) << 3;
  const int rs = (wave << 5) + (lane >> 2);
  const u16* ga0 = Wt + (long long)(m0 + rs) * 256 + cd;
  const u16* ga1 = ga0 + 16ll * 256;
  const u16* gb0 = Feat + (long long)perm_inv((z << 8) + n0 + rs)      * 256 + cd;
  const u16* gb1 = Feat + (long long)perm_inv((z << 8) + n0 + rs + 16) * 256 + cd;
  const int lofs = wave << 10;

  const int sw = ((((l15 >> 1) & 3) ^ quad) << 3);

  const f32x4 zero = {0.f, 0.f, 0.f, 0.f};
  f32x4 acc[4][4];
#pragma unroll
  for (int i = 0; i < 4; ++i)
#pragma unroll
    for (int j = 0; j < 4; ++j) acc[i][j] = zero;

  gl_lds16(ga0, &sA[0][lofs]);
  gl_lds16(ga1, &sA[0][lofs] + 512);
  gl_lds16(gb0, &sB[0][lofs]);
  gl_lds16(gb1, &sB[0][lofs] + 512);
  __syncthreads();

  int cur = 0;
  for (int k0 = 0; k0 < 256; k0 += 32) {
    if (k0 + 32 < 256) {
      const int nxt = cur ^ 1;
      gl_lds16(ga0 + k0 + 32, &sA[nxt][lofs]);
      gl_lds16(ga1 + k0 + 32, &sA[nxt][lofs] + 512);
      gl_lds16(gb0 + k0 + 32, &sB[nxt][lofs]);
      gl_lds16(gb1 + k0 + 32, &sB[nxt][lofs] + 512);
    }
    bf16x8 af[4], bfr[4];
#pragma unroll
    for (int i = 0; i < 4; ++i) {
      af[i]  = *(const bf16x8*)(&sA[cur][0] + ((wm + (i << 4) + l15) << 5) + sw);
      bfr[i] = *(const bf16x8*)(&sB[cur][0] + ((wn + (i << 4) + l15) << 5) + sw);
    }
#pragma unroll
    for (int i = 0; i < 4; ++i)
#pragma unroll
      for (int j = 0; j < 4; ++j)
        acc[i][j] = __builtin_amdgcn_mfma_f32_16x16x32_bf16(af[i], bfr[j], acc[i][j], 0, 0, 0);
    __syncthreads();
    cur ^= 1;
  }

#pragma unroll
  for (int i = 0; i < 4; ++i) {
#pragma unroll
    for (int r = 0; r < 4; ++r) {
      const int mg = m0 + wm + (i << 4) + (quad << 2) + r;
      u16* orow = Vt + (((long long)z) << 16) + ((long long)mg << 8);
#pragma unroll
      for (int j = 0; j < 4; ++j) {
        int ng = n0 + wn + (j << 4) + l15;
        orow[ng] = f2bf(acc[i][j][r]);
      }
    }
  }
}

// ---------- fused scores + mask + row softmax ----------
// Block = 128 q-rows x 256 k-cols of one window (grid (2, Wc)). Each wave owns
// 32 rows x all 256 cols: acc[2][16] (128 VGPR). Full rows block-local ->
// softmax in-epilogue; row reduce = in-lane over j then shfl_xor 1/2/4/8.
__global__ __launch_bounds__(256)
void scores_softmax(const u16* __restrict__ Q, const u16* __restrict__ Kw,
                    const float* __restrict__ mask, u16* __restrict__ SP)
{
  __shared__ __align__(16) u16 sA[2][128 * 32];
  __shared__ __align__(16) u16 sB[2][256 * 32];

  const int tid  = threadIdx.x;
  const int lane = tid & 63;
  const int wave = tid >> 6;
  const int l15  = lane & 15;
  const int quad = lane >> 4;

  const int mhalf = (int)blockIdx.x;
  const int z     = (int)blockIdx.y;
  const int m0    = mhalf << 7;

  const u16* Ab = Q  + ((long long)z << 16);
  const u16* Bb = Kw + ((long long)z << 16);

  // staging: A rows [32w,32w+32) (2 insts), B rows [64w,64w+64) (4 insts)
  const int cd  = ((lane & 3) ^ ((lane >> 3) & 3)) << 3;
  const int rsA = (wave << 5) + (lane >> 2);
  const int rsB = (wave << 6) + (lane >> 2);
  const u16* ga0 = Ab + (long long)(m0 + rsA) * 256 + cd;
  const u16* ga1 = ga0 + 16ll * 256;
  const u16* gb0 = Bb + (long long)rsB * 256 + cd;
  const int lofsA = wave << 10;
  const int lofsB = wave << 11;

  const int sw = ((((l15 >> 1) & 3) ^ quad) << 3);

  const f32x4 zero = {0.f, 0.f, 0.f, 0.f};
  f32x4 acc[2][16];
#pragma unroll
  for (int i = 0; i < 2; ++i)
#pragma unroll
    for (int j = 0; j < 16; ++j) acc[i][j] = zero;

  gl_lds16(ga0, &sA[0][lofsA]);
  gl_lds16(ga1, &sA[0][lofsA] + 512);
#pragma unroll
  for (int p = 0; p < 4; ++p)
    gl_lds16(gb0 + (p << 4) * 256, &sB[0][lofsB] + (p << 9));
  __syncthreads();

  int cur = 0;
  for (int k0 = 0; k0 < 256; k0 += 32) {
    if (k0 + 32 < 256) {
      const int nxt = cur ^ 1;
      gl_lds16(ga0 + k0 + 32, &sA[nxt][lofsA]);
      gl_lds16(ga1 + k0 + 32, &sA[nxt][lofsA] + 512);
#pragma unroll
      for (int p = 0; p < 4; ++p)
        gl_lds16(gb0 + k0 + 32 + (p << 4) * 256, &sB[nxt][lofsB] + (p << 9));
    }
    bf16x8 af0 = *(const bf16x8*)(&sA[cur][0] + (((wave << 5) + l15) << 5) + sw);
    bf16x8 af1 = *(const bf16x8*)(&sA[cur][0] + (((wave << 5) + 16 + l15) << 5) + sw);
#pragma unroll
    for (int j = 0; j < 16; ++j) {
      bf16x8 bf = *(const bf16x8*)(&sB[cur][0] + (((j << 4) + l15) << 5) + sw);
      acc[0][j] = __builtin_amdgcn_mfma_f32_16x16x32_bf16(af0, bf, acc[0][j], 0, 0, 0);
      acc[1][j] = __builtin_amdgcn_mfma_f32_16x16x32_bf16(af1, bf, acc[1][j], 0, 0, 0);
    }
    __syncthreads();
    cur ^= 1;
  }

  const float* mbase = mask + (((long long)(z & 63)) << 16);
#pragma unroll
  for (int i = 0; i < 2; ++i) {
#pragma unroll
    for (int r = 0; r < 4; ++r) {
      const int mg = m0 + (wave << 5) + (i << 4) + (quad << 2) + r;
      const float* mrow = mbase + ((long long)mg << 8);
      float sv[16];
      float mx = -3.0e38f;
#pragma unroll
      for (int j = 0; j < 16; ++j) {
        sv[j] = acc[i][j][r] * 0.0625f + mrow[(j << 4) + l15];
        mx = fmaxf(mx, sv[j]);
      }
#pragma unroll
      for (int o = 1; o < 16; o <<= 1) mx = fmaxf(mx, __shfl_xor(mx, o));
      float sum = 0.f;
#pragma unroll
      for (int j = 0; j < 16; ++j) { sv[j] = __expf(sv[j] - mx); sum += sv[j]; }
#pragma unroll
      for (int o = 1; o < 16; o <<= 1) sum += __shfl_xor(sum, o);
      const float inv = 1.0f / sum;
      u16* orow = SP + (((long long)z) << 16) + ((long long)mg << 8);
#pragma unroll
      for (int j = 0; j < 16; ++j) orow[(j << 4) + l15] = f2bf(sv[j] * inv);
    }
  }
}

// ---------- fused GEMM (M x 256, NT) + row LayerNorm epilogue ----------
// 64-row x 256-col tile, 4 waves x (16 rows x 256 cols), acc[16] (64 VGPR).
// R7 lesson: the 128-row variant hits ~220 VGPR + 48KB LDS -> 2 blocks/CU and
// regressed ~140us. Keep M=64 (40KB LDS, ~150 VGPR).
// Modes: LN_XCAT0: out=bf16(LN+ResF[fp32]) -> OutB[row*512 + 0:256]
//        LN_XCAT1: out=bf16(LN)            -> OutB[row*512 + 256:512]
//        LN_OUT:   out=fp32 LN + bf2f(ResB[row*512 + 0:256]) -> OutF[row*256]
enum { LN_XCAT0 = 0, LN_XCAT1 = 1, LN_OUT = 2 };

template<int MODE>
__global__ __launch_bounds__(256)
void gemm_ln(const u16* __restrict__ A, int lda,
             const u16* __restrict__ Bt,          // [256][K] bf16
             const float* __restrict__ G, const float* __restrict__ Bias,
             const float* __restrict__ ResF, const u16* __restrict__ ResB,
             float* __restrict__ OutF, u16* __restrict__ OutB, int K)
{
  __shared__ __align__(16) u16 sA[2][64 * 32];
  __shared__ __align__(16) u16 sB[2][256 * 32];

  const int tid  = threadIdx.x;
  const int lane = tid & 63;
  const int wave = tid >> 6;
  const int l15  = lane & 15;
  const int quad = lane >> 4;
  const int m0   = (int)blockIdx.x << 6;

  // staging: A rows [16w,16w+16) (1 inst), B rows [64w,64w+64) (4 insts)
  const int cd  = ((lane & 3) ^ ((lane >> 3) & 3)) << 3;
  const int rsA = (wave << 4) + (lane >> 2);
  const int rsB = (wave << 6) + (lane >> 2);
  const u16* ga0 = A  + (long long)(m0 + rsA) * lda + cd;
  const u16* gb0 = Bt + (long long)rsB * K + cd;
  const int lofsA = wave << 9;
  const int lofsB = wave << 11;

  const int sw = ((((l15 >> 1) & 3) ^ quad) << 3);

  const f32x4 zero = {0.f, 0.f, 0.f, 0.f};
  f32x4 acc[16];
#pragma unroll
  for (int j = 0; j < 16; ++j) acc[j] = zero;

  gl_lds16(ga0, &sA[0][lofsA]);
#pragma unroll
  for (int p = 0; p < 4; ++p)
    gl_lds16(gb0 + (long long)(p << 4) * K, &sB[0][lofsB] + (p << 9));
  __syncthreads();

  int cur = 0;
  for (int k0 = 0; k0 < K; k0 += 32) {
    if (k0 + 32 < K) {
      const int nxt = cur ^ 1;
      gl_lds16(ga0 + k0 + 32, &sA[nxt][lofsA]);
#pragma unroll
      for (int p = 0; p < 4; ++p)
        gl_lds16(gb0 + k0 + 32 + (long long)(p << 4) * K, &sB[nxt][lofsB] + (p << 9));
    }
    bf16x8 af = *(const bf16x8*)(&sA[cur][0] + (((wave << 4) + l15) << 5) + sw);
#pragma unroll
    for (int j = 0; j < 16; ++j) {
      bf16x8 bf = *(const bf16x8*)(&sB[cur][0] + (((j << 4) + l15) << 5) + sw);
      acc[j] = __builtin_amdgcn_mfma_f32_16x16x32_bf16(af, bf, acc[j], 0, 0, 0);
    }
    __syncthreads();
    cur ^= 1;
  }

  // per-thread gamma/beta for its 16 column slots
  float gj[16], bj[16];
#pragma unroll
  for (int j = 0; j < 16; ++j) {
    gj[j] = G[(j << 4) + l15];
    bj[j] = Bias[(j << 4) + l15];
  }

#pragma unroll
  for (int r = 0; r < 4; ++r) {
    const int mg = m0 + (wave << 4) + (quad << 2) + r;
    float s = 0.f, s2 = 0.f;
#pragma unroll
    for (int j = 0; j < 16; ++j) {
      float v = acc[j][r];
      s += v; s2 += v * v;
    }
#pragma unroll
    for (int o = 1; o < 16; o <<= 1) { s += __shfl_xor(s, o); s2 += __shfl_xor(s2, o); }
    const float mean = s * (1.0f / 256.0f);
    const float var  = s2 * (1.0f / 256.0f) - mean * mean;
    const float rstd = rsqrtf(var + 1e-5f);
    if constexpr (MODE == LN_XCAT0) {
      u16* orow = OutB + ((long long)mg << 9);
      const float* rrow = ResF + ((long long)mg << 8);
#pragma unroll
      for (int j = 0; j < 16; ++j) {
        float v = (acc[j][r] - mean) * rstd * gj[j] + bj[j];
        orow[(j << 4) + l15] = f2bf(v + rrow[(j << 4) + l15]);
      }
    } else if constexpr (MODE == LN_XCAT1) {
      u16* orow = OutB + ((long long)mg << 9) + 256;
#pragma unroll
      for (int j = 0; j < 16; ++j) {
        float v = (acc[j][r] - mean) * rstd * gj[j] + bj[j];
        orow[(j << 4) + l15] = f2bf(v);
      }
    } else { // LN_OUT
      const u16* rrow = ResB + ((long long)mg << 9);
      float* orow = OutF + ((long long)mg << 8);
#pragma unroll
      for (int j = 0; j < 16; ++j) {
        float v = (acc[j][r] - mean) * rstd * gj[j] + bj[j];
        orow[(j << 4) + l15] = v + bf2f(rrow[(j << 4) + l15]);
      }
    }
  }
}

// ---------- fp32 -> bf16 convert ----------
__global__ __launch_bounds__(256)
void cvt_f32_bf16(const float* __restrict__ src, u16* __restrict__ dst, int n4)
{
  int i = blockIdx.x * 256 + threadIdx.x;
  if (i >= n4) return;
  float4 v = ((const float4*)src)[i];
  ushort4 u; u.x = f2bf(v.x); u.y = f2bf(v.y); u.z = f2bf(v.z); u.w = f2bf(v.w);
  ((ushort4*)dst)[i] = u;
}

// ---------- weight transpose fp32 [R][C] -> bf16 [C][R] ----------
__global__ __launch_bounds__(256)
void wtrans(const float* __restrict__ src, u16* __restrict__ dst, int R, int C)
{
  int idx = blockIdx.x * 256 + threadIdx.x;
  if (idx >= R * C) return;
  int r = idx / C, c = idx - r * C;
  dst[c * R + r] = f2bf(src[idx]);
}

// ---------- w2 transpose with sigma column order matching FFN1's packed store ----
// w2: [2048][256] fp32 -> w2t: [256][2048] bf16 where column position q holds
// true hidden feature f = (q & ~63) | ((q&3)<<4) | ((q>>2)&15).
__global__ __launch_bounds__(256)
void wtrans_w2(const float* __restrict__ src, u16* __restrict__ dst)
{
  int idx = blockIdx.x * 256 + threadIdx.x;   // over 256*2048
  int c = idx >> 11, q = idx & 2047;
  int f = (q & ~63) | ((q & 3) << 4) | ((q >> 2) & 15);
  dst[idx] = f2bf(src[f * 256 + c]);
}

// ---------- orchestration ----------
extern "C" void kernel_launch(void* const* d_in, const int* in_sizes, int n_in,
                              void* d_out, int out_size, void* d_ws, size_t ws_size,
                              hipStream_t stream)
{
  (void)in_sizes; (void)n_in; (void)out_size;
  const float* feat0 = (const float*)d_in[0];
  const float* feat1 = (const float*)d_in[1];
  const float* mask  = (const float*)d_in[2];
  const float* wq1 = (const float*)d_in[6];
  const float* wk1 = (const float*)d_in[7];
  const float* wv1 = (const float*)d_in[8];
  const float* wf1 = (const float*)d_in[9];
  const float* g1  = (const float*)d_in[10];
  const float* b1  = (const float*)d_in[11];
  const float* wq2 = (const float*)d_in[12];
  const float* wk2 = (const float*)d_in[13];
  const float* wv2 = (const float*)d_in[14];
  const float* wf2 = (const float*)d_in[15];
  const float* g2  = (const float*)d_in[16];
  const float* b2  = (const float*)d_in[17];
  const float* w1  = (const float*)d_in[18];
  const float* w2  = (const float*)d_in[19];
  const float* fg  = (const float*)d_in[20];
  const float* fb  = (const float*)d_in[21];

  const size_t Mi = 1048576;
  const size_t WB = 4 * Mi;
  const int Mtot = 131072;

  int nc = 8;
  for (int c = 1; c <= 8; c <<= 1) {
    size_t S = (size_t)(Mtot / c) * 512;
    if (7 * S + WB <= ws_size) { nc = c; break; }
  }
  const int Mc = Mtot / nc;
  const size_t S = (size_t)Mc * 512;

  char* ws = (char*)d_ws;
  u16*   featb = (u16*)(ws);           // featN bf16; later scores SPb; later hbuf base
  u16*   SPb   = featb;
  u16*   qw    = (u16*)(ws + S);       // q windowed; later attn-out Ob
  u16*   Ob    = qw;
  u16*   hbuf  = featb;                // FFN hidden [MF=Mc/2, 2048] bf16 = 4S (featb..vw)
  u16*   kw    = (u16*)(ws + 2 * S);   // k windowed
  u16*   vt    = (u16*)(ws + 4 * S);   // v^T per window (written directly by gemm_vt)
  u16*   xcat  = (u16*)(ws + 5 * S);   // [Mc, 512] bf16: [f0 | a2]
  u16*   wb    = (u16*)(ws + 7 * S);
  u16* wq1t = wb;            u16* wk1t = wb + 65536;  u16* wv1t = wb + 131072; u16* wf1t = wb + 196608;
  u16* wq2t = wb + 262144;   u16* wk2t = wb + 327680; u16* wv2t = wb + 393216; u16* wf2t = wb + 458752;
  u16* w1t  = wb + 524288;               // [2048][512]
  u16* w2t  = wb + 524288 + 1048576;     // [256][2048] sigma-ordered

  const dim3 blk(256);
  const dim3 gBig(2, Mc / 128, 1);     // N=256 GEMMs
  const dim3 gQK(4, Mc / 128, 1);      // merged q|k (N=512; wq1t/wk1t adjacent)
  const int  Wc = Mc / 256;
  const dim3 gWin(2, 2, Wc);
  const dim3 gSS(2, Wc);
  const int  gRows = Mc / 4;
  const int  gLN   = Mc / 64;          // fused gemm+ln blocks (64 rows each)
  const int  MF = Mc / 2;              // FFN M-chunk rows (hbuf = 4S fits [0,4S))
  const dim3 gF1(16, MF / 128, 1);
  const int  gLNF  = MF / 64;

  wtrans<<<256, blk, 0, stream>>>(wq1, wq1t, 256, 256);
  wtrans<<<256, blk, 0, stream>>>(wk1, wk1t, 256, 256);
  wtrans<<<256, blk, 0, stream>>>(wv1, wv1t, 256, 256);
  wtrans<<<256, blk, 0, stream>>>(wf1, wf1t, 256, 256);
  wtrans<<<256, blk, 0, stream>>>(wq2, wq2t, 256, 256);
  wtrans<<<256, blk, 0, stream>>>(wk2, wk2t, 256, 256);
  wtrans<<<256, blk, 0, stream>>>(wv2, wv2t, 256, 256);
  wtrans<<<256, blk, 0, stream>>>(wf2, wf2t, 256, 256);
  wtrans<<<4096, blk, 0, stream>>>(w1, w1t, 512, 2048);
  wtrans_w2<<<2048, blk, 0, stream>>>(w2, w2t);

  const int qkStride = Mc * 256;       // elems between qw and kw buffers

  for (int c = 0; c < nc; ++c) {
    const long long off = (long long)c * Mc * 256;
    const float* f0in = feat0 + off;
    const float* f1in = feat1 + off;
    float* outp = (float*)d_out + off;

    // ---- Block 1 (intra) ----
    cvt_f32_bf16<<<gRows, blk, 0, stream>>>(f0in, featb, Mc * 64);
    gemm_nt<MODE_QKV><<<gQK, blk, 0, stream>>>(featb, 256, 0, wq1t, 256, 0, qw, nullptr, nullptr, 256, qkStride);
    gemm_vt<<<gWin, blk, 0, stream>>>(wv1t, featb, vt);
    scores_softmax<<<gSS, blk, 0, stream>>>(qw, kw, mask, SPb);
    gemm_nt<MODE_PV><<<gWin, blk, 0, stream>>>(SPb, 256, 65536, vt, 256, 65536, Ob, nullptr, nullptr, 256, 0);
    gemm_ln<LN_XCAT0><<<gLN, blk, 0, stream>>>(Ob, 256, wf1t, g1, b1, f0in, nullptr, nullptr, xcat, 256);

    // ---- Block 2 (inter) ----
    cvt_f32_bf16<<<gRows, blk, 0, stream>>>(f1in, featb, Mc * 64);
    gemm_nt<MODE_QKV><<<gBig, blk, 0, stream>>>(xcat, 512, 0, wq2t, 256, 0, qw, nullptr, nullptr, 512, 0);
    gemm_nt<MODE_QKV><<<gBig, blk, 0, stream>>>(featb, 256, 0, wk2t, 256, 0, kw, nullptr, nullptr, 256, 0);
    gemm_vt<<<gWin, blk, 0, stream>>>(wv2t, featb, vt);
    scores_softmax<<<gSS, blk, 0, stream>>>(qw, kw, mask, SPb);
    gemm_nt<MODE_PV><<<gWin, blk, 0, stream>>>(SPb, 256, 65536, vt, 256, 65536, Ob, nullptr, nullptr, 256, 0);
    gemm_ln<LN_XCAT1><<<gLN, blk, 0, stream>>>(Ob, 256, wf2t, g2, b2, nullptr, nullptr, nullptr, xcat, 256);

    // ---- FFN: 2 M-chunks; hbuf spans [0,4S) (featb/qw/kw regions all dead) ----
    for (int mc = 0; mc < 2; ++mc) {
      const u16* xc = xcat + (long long)mc * MF * 512;
      gemm_nt<MODE_FFN1><<<gF1, blk, 0, stream>>>(xc, 512, 0, w1t, 512, 0,
                                                  hbuf, nullptr, nullptr, 512, 2048);
      gemm_ln<LN_OUT><<<gLNF, blk, 0, stream>>>(hbuf, 2048, w2t, fg, fb, nullptr,
                                                xcat + (long long)mc * MF * 512,
                                                outp + (long long)mc * MF * 256, nullptr, 2048);
    }
  }
}

// Round 10
// 1628.903 us; speedup vs baseline: 1.1276x; 1.1276x over previous
//
#include <hip/hip_runtime.h>

typedef unsigned short u16;
typedef unsigned int   u32;

using f32x4  = __attribute__((ext_vector_type(4))) float;
using bf16x8 = __attribute__((ext_vector_type(8))) __bf16;

// ---------- helpers ----------
// native cast: clang lowers fptrunc f32->bf16 on gfx950 to v_cvt_pk_bf16_f32 (RNE)
__device__ inline u16 f2bf(float f) {
  return __builtin_bit_cast(u16, (__bf16)f);
}
__device__ inline float bf2f(u16 v) {
  u32 u = ((u32)v) << 16;
  return __builtin_bit_cast(float, u);
}
// packed f32x2 -> bf16x2 (RNE), lo = a, hi = b
__device__ inline u32 pk_bf16(float a, float b) {
  u32 d;
  asm("v_cvt_pk_bf16_f32 %0, %1, %2" : "=v"(d) : "v"(a), "v"(b));
  return d;
}

// async global->LDS, 16B per lane; LDS dst is wave-uniform base + lane*16,
// global src is PER-LANE (enables permuted-row staging, see gemm_vt).
__device__ inline void gl_lds16(const u16* g, u16* l) {
  __builtin_amdgcn_global_load_lds((const __attribute__((address_space(1))) void*)g,
                                   (__attribute__((address_space(3))) void*)l,
                                   16, 0, 0);
}

// Geometry: B=8, H=W=128, NW=8, win=16x16 (N=256), D=256, shift=8. Chunk-local.
__device__ inline int perm_fwd(int m) {
  int b = m >> 14, rem = m & 16383;
  int h = rem >> 7, w = rem & 127;
  int hr = (h - 8) & 127, wr = (w - 8) & 127;
  int win = (b << 6) | ((hr >> 4) << 3) | (wr >> 4);
  return (win << 8) | ((hr & 15) << 4) | (wr & 15);
}
__device__ inline int perm_inv(int r) {
  int win = r >> 8, t = r & 255;
  int b = win >> 6, wy = (win >> 3) & 7, wx = win & 7;
  int h = (((wy << 4) | (t >> 4)) + 8) & 127;
  int w = (((wx << 4) | (t & 15)) + 8) & 127;
  return (b << 14) | (h << 7) | w;
}

// ---------- 128x128x(BK=64) NT GEMM, bf16 in / fp32 acc, global_load_lds staging ----------
// Single-buffer (32KB LDS, ~2.5 blocks/CU). Schedule ledger: R3 dbuf-64KB (occupancy
// loss), R9 BK=32 dbuf (compute phase too short to cover latency; VALUBusy 58->39),
// R4 XCD swizzle (L3-resident, latency-bound), R7 M=128 LN tile (VGPR+LDS occupancy)
// — ALL regressed. This single-buffer BK=64 structure is the local optimum; it lives
// on wave-level TLP.
// LDS tile: 128 rows x 64 elems (128B rows, 8 chunks of 16B).
// XOR swizzle: slot s of row r holds data chunk s ^ (r&7). No padding
// (required by global_load_lds linear dest). Reads are <=2-way bank-aliased.
// SIGMA-PACK epilogues (R7 win, -4% on FFN1): store col within each 64-col group at
// pos = l15*4+j (true feature f = (pos&3)<<4 | pos>>2). Valid whenever both sides of
// the consuming dot product carry the same sigma (Q&K; Ob&wfc-k; hbuf&w2-k), since
// dot products are permutation-invariant. 2x cvt_pk + 1 dwordx2 store replaces
// 4 cvt + 4 scalar stores.

enum { MODE_QKV = 0, MODE_PV = 2, MODE_FFN1 = 4 };

template<int MODE>
__global__ __launch_bounds__(256)
void gemm_nt(const u16* __restrict__ A, int lda, long long sAz,
             const u16* __restrict__ Bt, int ldb, long long sBz,
             u16* __restrict__ OutB, float* __restrict__ OutF,
             const float* __restrict__ mask, int K, int ldo)
{
  __shared__ __align__(16) u16 sA[128 * 64];
  __shared__ __align__(16) u16 sB[128 * 64];

  const int tid  = threadIdx.x;
  const int lane = tid & 63;
  const int wave = tid >> 6;
  const int l15  = lane & 15;
  const int quad = lane >> 4;
  const int wm   = (wave >> 1) << 6;
  const int wn   = (wave & 1) << 6;
  const int z    = blockIdx.z;
  const int m0   = (int)(blockIdx.y) << 7;
  const int n0   = (int)(blockIdx.x) << 7;

  const u16* Ab = A  + (long long)z * sAz;
  const u16* Bb = Bt + (long long)z * sBz;

  // staging: wave w stages rows [32w, 32w+32) of A and B.
  // 4 gl_lds16 per matrix per wave; instruction p covers rows [32w+8p, 32w+8p+8).
  // lane l: row-in-8 = l>>3, slot = l&7, data chunk = (l&7)^((l>>3)&7)
  const int cd = ((lane & 7) ^ ((lane >> 3) & 7)) << 3;   // elems
  const int rs = (wave << 5) + (lane >> 3);
  const u16* ga0 = Ab + (long long)(m0 + rs) * lda + cd;
  const u16* gb0 = Bb + (long long)(n0 + rs) * ldb + cd;
  u16* la0 = &sA[wave << 11];
  u16* lb0 = &sB[wave << 11];

  const f32x4 zero = {0.f, 0.f, 0.f, 0.f};
  f32x4 acc[4][4];
#pragma unroll
  for (int i = 0; i < 4; ++i)
#pragma unroll
    for (int j = 0; j < 4; ++j) acc[i][j] = zero;

  for (int k0 = 0; k0 < K; k0 += 64) {
    __syncthreads();
#pragma unroll
    for (int p = 0; p < 4; ++p) {
      gl_lds16(ga0 + k0 + (p << 3) * lda, la0 + (p << 9));
      gl_lds16(gb0 + k0 + (p << 3) * ldb, lb0 + (p << 9));
    }
    __syncthreads();
#pragma unroll
    for (int kk = 0; kk < 2; ++kk) {
      // fragment read: row R = wm/wn + i*16 + l15, data chunk d = quad + 4*kk,
      // slot = d ^ (R&7) = (quad | kk<<2) ^ (l15&7)
      const int sw = (((quad | (kk << 2)) ^ (l15 & 7)) << 3);
      bf16x8 af[4], bfr[4];
#pragma unroll
      for (int i = 0; i < 4; ++i) {
        af[i]  = *(const bf16x8*)(sA + ((wm + (i << 4) + l15) << 6) + sw);
        bfr[i] = *(const bf16x8*)(sB + ((wn + (i << 4) + l15) << 6) + sw);
      }
#pragma unroll
      for (int i = 0; i < 4; ++i)
#pragma unroll
        for (int j = 0; j < 4; ++j)
          acc[i][j] = __builtin_amdgcn_mfma_f32_16x16x32_bf16(af[i], bfr[j], acc[i][j], 0, 0, 0);
    }
  }

  // epilogue: D[row=quad*4+r][col=l15]
#pragma unroll
  for (int i = 0; i < 4; ++i) {
#pragma unroll
    for (int r = 0; r < 4; ++r) {
      int mg = m0 + wm + (i << 4) + (quad << 2) + r;
      if constexpr (MODE == MODE_QKV) {
        // merged q|k: buffer select by n0>>8 (rows 0:256 of B -> buf0, 256:512 -> buf1).
        // SIGMA-PACK: Q and K share the same sigma -> QK^T over d invariant.
        u16* orow = OutB + (long long)(n0 >> 8) * ldo + ((long long)perm_fwd(mg) << 8);
        uint2 d;
        d.x = pk_bf16(acc[i][0][r], acc[i][1][r]);
        d.y = pk_bf16(acc[i][2][r], acc[i][3][r]);
        *(uint2*)(orow + (n0 & 128) + wn + (l15 << 2)) = d;
      } else if constexpr (MODE == MODE_PV) {
        // SIGMA-PACK: Ob cols sigma'd; consumer gemm_ln uses k-sigma'd wf1t/wf2t.
        u16* orow = OutB + ((long long)perm_inv((z << 8) + mg) << 8);
        uint2 d;
        d.x = pk_bf16(acc[i][0][r], acc[i][1][r]);
        d.y = pk_bf16(acc[i][2][r], acc[i][3][r]);
        *(uint2*)(orow + n0 + wn + (l15 << 2)) = d;
      } else { // MODE_FFN1: tanh-approx gelu -> bf16, SIGMA-PACKED cols, ld = ldo
        // gelu(v) ~= v * sigmoid(1.5957691216*v + 0.071354816*v^3)
        // max |err| vs exact erf-gelu ~3e-4, below bf16 quantization of the
        // hidden activations. Overflow-safe: exp->inf => rcp->0 => g->-0.
        float gv[4];
#pragma unroll
        for (int j = 0; j < 4; ++j) {
          float v = acc[i][j][r];
          float t = v * fmaf(v * v, -0.071354816f, -1.5957691216f);
          gv[j] = v * __builtin_amdgcn_rcpf(1.0f + __expf(t));
        }
        uint2 d;
        d.x = pk_bf16(gv[0], gv[1]);
        d.y = pk_bf16(gv[2], gv[3]);
        *(uint2*)(OutB + (long long)mg * ldo + n0 + wn + (l15 << 2)) = d;
      }
    }
  }
}

// ---------- direct per-window V^T GEMM ----------
// vt[z][d][t] = sum_k wvt[d][k] * feat[perm_inv(z*256+t)][k].
// B-staging exploits gl_lds16's PER-LANE global source: each lane loads from
// the permuted feat row while the LDS dest stays linear (same XOR col-swizzle:
// row-in-8 = lane>>3 is preserved, so slot s of LDS row r holds chunk s^(r&7)).
__global__ __launch_bounds__(256)
void gemm_vt(const u16* __restrict__ Wt,    // [256][256] bf16 = wv^T (L2-hot)
             const u16* __restrict__ Feat,  // [Mc][256] bf16 unpermuted
             u16* __restrict__ Vt)          // [Wc][256][256]
{
  __shared__ __align__(16) u16 sA[128 * 64];
  __shared__ __align__(16) u16 sB[128 * 64];

  const int tid  = threadIdx.x;
  const int lane = tid & 63;
  const int wave = tid >> 6;
  const int l15  = lane & 15;
  const int quad = lane >> 4;
  const int wm   = (wave >> 1) << 6;
  const int wn   = (wave & 1) << 6;
  const int z    = blockIdx.z;
  const int m0   = (int)(blockIdx.y) << 7;   // d-tile
  const int n0   = (int)(blockIdx.x) << 7;   // t-tile

  const int cd = ((lane & 7) ^ ((lane >> 3) & 7)) << 3;
  const int rs = (wave << 5) + (lane >> 3);
  const u16* ga0 = Wt + (long long)(m0 + rs) * 256 + cd;
  const u16* gb0 = Feat + (long long)perm_inv((z << 8) + n0 + rs)        * 256 + cd;
  const u16* gb1 = Feat + (long long)perm_inv((z << 8) + n0 + rs + 8)    * 256 + cd;
  const u16* gb2 = Feat + (long long)perm_inv((z << 8) + n0 + rs + 16)   * 256 + cd;
  const u16* gb3 = Feat + (long long)perm_inv((z << 8) + n0 + rs + 24)   * 256 + cd;
  u16* la0 = &sA[wave << 11];
  u16* lb0 = &sB[wave << 11];

  const f32x4 zero = {0.f, 0.f, 0.f, 0.f};
  f32x4 acc[4][4];
#pragma unroll
  for (int i = 0; i < 4; ++i)
#pragma unroll
    for (int j = 0; j < 4; ++j) acc[i][j] = zero;

  for (int k0 = 0; k0 < 256; k0 += 64) {
    __syncthreads();
#pragma unroll
    for (int p = 0; p < 4; ++p)
      gl_lds16(ga0 + k0 + (p << 3) * 256, la0 + (p << 9));
    gl_lds16(gb0 + k0, lb0);
    gl_lds16(gb1 + k0, lb0 + 512);
    gl_lds16(gb2 + k0, lb0 + 1024);
    gl_lds16(gb3 + k0, lb0 + 1536);
    __syncthreads();
#pragma unroll
    for (int kk = 0; kk < 2; ++kk) {
      const int sw = (((quad | (kk << 2)) ^ (l15 & 7)) << 3);
      bf16x8 af[4], bfr[4];
#pragma unroll
      for (int i = 0; i < 4; ++i) {
        af[i]  = *(const bf16x8*)(sA + ((wm + (i << 4) + l15) << 6) + sw);
        bfr[i] = *(const bf16x8*)(sB + ((wn + (i << 4) + l15) << 6) + sw);
      }
#pragma unroll
      for (int i = 0; i < 4; ++i)
#pragma unroll
        for (int j = 0; j < 4; ++j)
          acc[i][j] = __builtin_amdgcn_mfma_f32_16x16x32_bf16(af[i], bfr[j], acc[i][j], 0, 0, 0);
    }
  }

#pragma unroll
  for (int i = 0; i < 4; ++i) {
#pragma unroll
    for (int r = 0; r < 4; ++r) {
      const int mg = m0 + wm + (i << 4) + (quad << 2) + r;
      u16* orow = Vt + (((long long)z) << 16) + ((long long)mg << 8);
#pragma unroll
      for (int j = 0; j < 4; ++j) {
        int ng = n0 + wn + (j << 4) + l15;
        orow[ng] = f2bf(acc[i][j][r]);
      }
    }
  }
}

// ---------- fused scores + mask + row softmax ----------
// Block = 128 q-rows x 256 k-cols of one window (grid (2, Wc)). Each wave owns
// 32 rows x all 256 cols: acc[2][16] (128 VGPR). Full rows block-local ->
// softmax in-epilogue: row = (i,quad,r); 16 lanes (l15) x 16 frags (j) hold the
// 256 cols; row reduce = in-lane over j then shfl_xor 1/2/4/8 (stays in quad).
// Q/K are sigma-packed in d (both sides) -> QK^T unchanged.
__global__ __launch_bounds__(256)
void scores_softmax(const u16* __restrict__ Q, const u16* __restrict__ Kw,
                    const float* __restrict__ mask, u16* __restrict__ SP)
{
  __shared__ __align__(16) u16 sA[128 * 64];
  __shared__ __align__(16) u16 sB[256 * 64];

  const int tid  = threadIdx.x;
  const int lane = tid & 63;
  const int wave = tid >> 6;
  const int l15  = lane & 15;
  const int quad = lane >> 4;

  const int mhalf = (int)blockIdx.x;
  const int z     = (int)blockIdx.y;
  const int m0    = mhalf << 7;

  const u16* Ab = Q  + ((long long)z << 16);
  const u16* Bb = Kw + ((long long)z << 16);

  // staging (same swizzle as gemm_nt): A rows [32w,32w+32), B rows [64w,64w+64)
  const int cd  = ((lane & 7) ^ ((lane >> 3) & 7)) << 3;
  const int rsA = (wave << 5) + (lane >> 3);
  const int rsB = (wave << 6) + (lane >> 3);
  const u16* ga0 = Ab + (long long)(m0 + rsA) * 256 + cd;
  const u16* gb0 = Bb + (long long)rsB * 256 + cd;
  u16* la0 = &sA[wave << 11];
  u16* lb0 = &sB[wave << 12];

  const f32x4 zero = {0.f, 0.f, 0.f, 0.f};
  f32x4 acc[2][16];
#pragma unroll
  for (int i = 0; i < 2; ++i)
#pragma unroll
    for (int j = 0; j < 16; ++j) acc[i][j] = zero;

  for (int k0 = 0; k0 < 256; k0 += 64) {
    __syncthreads();
#pragma unroll
    for (int p = 0; p < 4; ++p)
      gl_lds16(ga0 + k0 + (p << 3) * 256, la0 + (p << 9));
#pragma unroll
    for (int p = 0; p < 8; ++p)
      gl_lds16(gb0 + k0 + (p << 3) * 256, lb0 + (p << 9));
    __syncthreads();
#pragma unroll
    for (int kk = 0; kk < 2; ++kk) {
      const int sw = (((quad | (kk << 2)) ^ (l15 & 7)) << 3);
      bf16x8 af0 = *(const bf16x8*)(sA + (((wave << 5) + l15) << 6) + sw);
      bf16x8 af1 = *(const bf16x8*)(sA + (((wave << 5) + 16 + l15) << 6) + sw);
#pragma unroll
      for (int j = 0; j < 16; ++j) {
        bf16x8 bf = *(const bf16x8*)(sB + (((j << 4) + l15) << 6) + sw);
        acc[0][j] = __builtin_amdgcn_mfma_f32_16x16x32_bf16(af0, bf, acc[0][j], 0, 0, 0);
        acc[1][j] = __builtin_amdgcn_mfma_f32_16x16x32_bf16(af1, bf, acc[1][j], 0, 0, 0);
      }
    }
  }

  const float* mbase = mask + (((long long)(z & 63)) << 16);
#pragma unroll
  for (int i = 0; i < 2; ++i) {
#pragma unroll
    for (int r = 0; r < 4; ++r) {
      const int mg = m0 + (wave << 5) + (i << 4) + (quad << 2) + r;
      const float* mrow = mbase + ((long long)mg << 8);
      float sv[16];
      float mx = -3.0e38f;
#pragma unroll
      for (int j = 0; j < 16; ++j) {
        sv[j] = acc[i][j][r] * 0.0625f + mrow[(j << 4) + l15];
        mx = fmaxf(mx, sv[j]);
      }
#pragma unroll
      for (int o = 1; o < 16; o <<= 1) mx = fmaxf(mx, __shfl_xor(mx, o));
      float sum = 0.f;
#pragma unroll
      for (int j = 0; j < 16; ++j) { sv[j] = __expf(sv[j] - mx); sum += sv[j]; }
#pragma unroll
      for (int o = 1; o < 16; o <<= 1) sum += __shfl_xor(sum, o);
      const float inv = 1.0f / sum;
      u16* orow = SP + (((long long)z) << 16) + ((long long)mg << 8);
#pragma unroll
      for (int j = 0; j < 16; ++j) orow[(j << 4) + l15] = f2bf(sv[j] * inv);
    }
  }
}

// ---------- fused GEMM (M x 256, NT) + row LayerNorm epilogue ----------
// 64-row x 256-col tile, 4 waves x (16 rows x 256 cols), acc[16] (64 VGPR).
// R7 lesson: the 128-row variant hits ~220 VGPR + 48KB LDS -> 2 blocks/CU and
// regressed ~140us. Keep M=64 (40KB LDS, ~150 VGPR).
// Full rows block-local -> LN in-epilogue via in-lane sum over 16 frags +
// shfl_xor 1/2/4/8 across l15 (same reduction topology as scores_softmax).
// Modes: LN_XCAT0: out=bf16(LN+ResF[fp32]) -> OutB[row*512 + 0:256]
//        LN_XCAT1: out=bf16(LN)            -> OutB[row*512 + 256:512]
//        LN_OUT:   out=fp32 LN + bf2f(ResB[row*512 + 0:256]) -> OutF[row*256]
enum { LN_XCAT0 = 0, LN_XCAT1 = 1, LN_OUT = 2 };

template<int MODE>
__global__ __launch_bounds__(256)
void gemm_ln(const u16* __restrict__ A, int lda,
             const u16* __restrict__ Bt,          // [256][K] bf16 (k-dim sigma'd to match A)
             const float* __restrict__ G, const float* __restrict__ Bias,
             const float* __restrict__ ResF, const u16* __restrict__ ResB,
             float* __restrict__ OutF, u16* __restrict__ OutB, int K)
{
  __shared__ __align__(16) u16 sA[64 * 64];
  __shared__ __align__(16) u16 sB[256 * 64];

  const int tid  = threadIdx.x;
  const int lane = tid & 63;
  const int wave = tid >> 6;
  const int l15  = lane & 15;
  const int quad = lane >> 4;
  const int m0   = (int)blockIdx.x << 6;

  // staging: wave w stages A rows [16w,16w+16) (2 insts) and B rows [64w,64w+64) (8 insts)
  const int cd  = ((lane & 7) ^ ((lane >> 3) & 7)) << 3;
  const int rsA = (wave << 4) + (lane >> 3);
  const int rsB = (wave << 6) + (lane >> 3);
  const u16* ga0 = A  + (long long)(m0 + rsA) * lda + cd;
  const u16* gb0 = Bt + (long long)rsB * K + cd;
  u16* la0 = &sA[wave << 10];
  u16* lb0 = &sB[wave << 12];

  const f32x4 zero = {0.f, 0.f, 0.f, 0.f};
  f32x4 acc[16];
#pragma unroll
  for (int j = 0; j < 16; ++j) acc[j] = zero;

  for (int k0 = 0; k0 < K; k0 += 64) {
    __syncthreads();
#pragma unroll
    for (int p = 0; p < 2; ++p)
      gl_lds16(ga0 + k0 + (p << 3) * lda, la0 + (p << 9));
#pragma unroll
    for (int p = 0; p < 8; ++p)
      gl_lds16(gb0 + k0 + (p << 3) * K, lb0 + (p << 9));
    __syncthreads();
#pragma unroll
    for (int kk = 0; kk < 2; ++kk) {
      const int sw = (((quad | (kk << 2)) ^ (l15 & 7)) << 3);
      bf16x8 af = *(const bf16x8*)(sA + (((wave << 4) + l15) << 6) + sw);
#pragma unroll
      for (int j = 0; j < 16; ++j) {
        bf16x8 bf = *(const bf16x8*)(sB + (((j << 4) + l15) << 6) + sw);
        acc[j] = __builtin_amdgcn_mfma_f32_16x16x32_bf16(af, bf, acc[j], 0, 0, 0);
      }
    }
  }

  // per-thread gamma/beta for its 16 column slots
  float gj[16], bj[16];
#pragma unroll
  for (int j = 0; j < 16; ++j) {
    gj[j] = G[(j << 4) + l15];
    bj[j] = Bias[(j << 4) + l15];
  }

#pragma unroll
  for (int r = 0; r < 4; ++r) {
    const int mg = m0 + (wave << 4) + (quad << 2) + r;
    float s = 0.f, s2 = 0.f;
#pragma unroll
    for (int j = 0; j < 16; ++j) {
      float v = acc[j][r];
      s += v; s2 += v * v;
    }
#pragma unroll
    for (int o = 1; o < 16; o <<= 1) { s += __shfl_xor(s, o); s2 += __shfl_xor(s2, o); }
    const float mean = s * (1.0f / 256.0f);
    const float var  = s2 * (1.0f / 256.0f) - mean * mean;
    const float rstd = rsqrtf(var + 1e-5f);
    if constexpr (MODE == LN_XCAT0) {
      u16* orow = OutB + ((long long)mg << 9);
      const float* rrow = ResF + ((long long)mg << 8);
#pragma unroll
      for (int j = 0; j < 16; ++j) {
        float v = (acc[j][r] - mean) * rstd * gj[j] + bj[j];
        orow[(j << 4) + l15] = f2bf(v + rrow[(j << 4) + l15]);
      }
    } else if constexpr (MODE == LN_XCAT1) {
      u16* orow = OutB + ((long long)mg << 9) + 256;
#pragma unroll
      for (int j = 0; j < 16; ++j) {
        float v = (acc[j][r] - mean) * rstd * gj[j] + bj[j];
        orow[(j << 4) + l15] = f2bf(v);
      }
    } else { // LN_OUT
      const u16* rrow = ResB + ((long long)mg << 9);
      float* orow = OutF + ((long long)mg << 8);
#pragma unroll
      for (int j = 0; j < 16; ++j) {
        float v = (acc[j][r] - mean) * rstd * gj[j] + bj[j];
        orow[(j << 4) + l15] = v + bf2f(rrow[(j << 4) + l15]);
      }
    }
  }
}

// ---------- fp32 -> bf16 convert ----------
__global__ __launch_bounds__(256)
void cvt_f32_bf16(const float* __restrict__ src, u16* __restrict__ dst, int n4)
{
  int i = blockIdx.x * 256 + threadIdx.x;
  if (i >= n4) return;
  float4 v = ((const float4*)src)[i];
  ushort4 u; u.x = f2bf(v.x); u.y = f2bf(v.y); u.z = f2bf(v.z); u.w = f2bf(v.w);
  ((ushort4*)dst)[i] = u;
}

// ---------- weight transpose fp32 [R][C] -> bf16 [C][R] ----------
__global__ __launch_bounds__(256)
void wtrans(const float* __restrict__ src, u16* __restrict__ dst, int R, int C)
{
  int idx = blockIdx.x * 256 + threadIdx.x;
  if (idx >= R * C) return;
  int r = idx / C, c = idx - r * C;
  dst[c * R + r] = f2bf(src[idx]);
}

// ---------- 256x256 weight transpose with sigma'd k (cols) ----------
// src [256 k][256 n] fp32 -> dst [256 n][256 k-pos] bf16 where k-pos q holds
// true k f = (q & ~63) | ((q&3)<<4) | ((q>>2)&15). Pairs with sigma-packed
// A operands (Ob from MODE_PV).
__global__ __launch_bounds__(256)
void wtrans_sig(const float* __restrict__ src, u16* __restrict__ dst)
{
  int idx = blockIdx.x * 256 + threadIdx.x;   // over 256*256
  int n = idx >> 8, q = idx & 255;
  int f = (q & ~63) | ((q & 3) << 4) | ((q >> 2) & 15);
  dst[idx] = f2bf(src[f * 256 + n]);
}

// ---------- w2 transpose with sigma column order matching FFN1's packed store ----
// w2: [2048][256] fp32 -> w2t: [256][2048] bf16 where column position q holds
// true hidden feature f = (q & ~63) | ((q&3)<<4) | ((q>>2)&15).
__global__ __launch_bounds__(256)
void wtrans_w2(const float* __restrict__ src, u16* __restrict__ dst)
{
  int idx = blockIdx.x * 256 + threadIdx.x;   // over 256*2048
  int c = idx >> 11, q = idx & 2047;
  int f = (q & ~63) | ((q & 3) << 4) | ((q >> 2) & 15);
  dst[idx] = f2bf(src[f * 256 + c]);
}

// ---------- orchestration ----------
extern "C" void kernel_launch(void* const* d_in, const int* in_sizes, int n_in,
                              void* d_out, int out_size, void* d_ws, size_t ws_size,
                              hipStream_t stream)
{
  (void)in_sizes; (void)n_in; (void)out_size;
  const float* feat0 = (const float*)d_in[0];
  const float* feat1 = (const float*)d_in[1];
  const float* mask  = (const float*)d_in[2];
  const float* wq1 = (const float*)d_in[6];
  const float* wk1 = (const float*)d_in[7];
  const float* wv1 = (const float*)d_in[8];
  const float* wf1 = (const float*)d_in[9];
  const float* g1  = (const float*)d_in[10];
  const float* b1  = (const float*)d_in[11];
  const float* wq2 = (const float*)d_in[12];
  const float* wk2 = (const float*)d_in[13];
  const float* wv2 = (const float*)d_in[14];
  const float* wf2 = (const float*)d_in[15];
  const float* g2  = (const float*)d_in[16];
  const float* b2  = (const float*)d_in[17];
  const float* w1  = (const float*)d_in[18];
  const float* w2  = (const float*)d_in[19];
  const float* fg  = (const float*)d_in[20];
  const float* fb  = (const float*)d_in[21];

  const size_t Mi = 1048576;
  const size_t WB = 4 * Mi;
  const int Mtot = 131072;

  int nc = 8;
  for (int c = 1; c <= 8; c <<= 1) {
    size_t S = (size_t)(Mtot / c) * 512;
    if (7 * S + WB <= ws_size) { nc = c; break; }
  }
  const int Mc = Mtot / nc;
  const size_t S = (size_t)Mc * 512;

  char* ws = (char*)d_ws;
  u16*   featb = (u16*)(ws);           // featN bf16; later scores SPb; later hbuf base
  u16*   SPb   = featb;
  u16*   qw    = (u16*)(ws + S);       // q windowed; later attn-out Ob
  u16*   Ob    = qw;
  u16*   hbuf  = featb;                // FFN hidden [MF=Mc/2, 2048] bf16 = 4S (featb..vw)
  u16*   kw    = (u16*)(ws + 2 * S);   // k windowed
  u16*   vt    = (u16*)(ws + 4 * S);   // v^T per window (written directly by gemm_vt)
  u16*   xcat  = (u16*)(ws + 5 * S);   // [Mc, 512] bf16: [f0 | a2]
  u16*   wb    = (u16*)(ws + 7 * S);
  u16* wq1t = wb;            u16* wk1t = wb + 65536;  u16* wv1t = wb + 131072; u16* wf1t = wb + 196608;
  u16* wq2t = wb + 262144;   u16* wk2t = wb + 327680; u16* wv2t = wb + 393216; u16* wf2t = wb + 458752;
  u16* w1t  = wb + 524288;               // [2048][512]
  u16* w2t  = wb + 524288 + 1048576;     // [256][2048] sigma-ordered

  const dim3 blk(256);
  const dim3 gBig(2, Mc / 128, 1);     // N=256 GEMMs
  const dim3 gQK(4, Mc / 128, 1);      // merged q|k (N=512; wq1t/wk1t adjacent)
  const int  Wc = Mc / 256;
  const dim3 gWin(2, 2, Wc);
  const dim3 gSS(2, Wc);
  const int  gRows = Mc / 4;
  const int  gLN   = Mc / 64;          // fused gemm+ln blocks (64 rows each)
  const int  MF = Mc / 2;              // FFN M-chunk rows (hbuf = 4S fits [0,4S))
  const dim3 gF1(16, MF / 128, 1);
  const int  gLNF  = MF / 64;

  wtrans<<<256, blk, 0, stream>>>(wq1, wq1t, 256, 256);
  wtrans<<<256, blk, 0, stream>>>(wk1, wk1t, 256, 256);
  wtrans<<<256, blk, 0, stream>>>(wv1, wv1t, 256, 256);
  wtrans_sig<<<256, blk, 0, stream>>>(wf1, wf1t);
  wtrans<<<256, blk, 0, stream>>>(wq2, wq2t, 256, 256);
  wtrans<<<256, blk, 0, stream>>>(wk2, wk2t, 256, 256);
  wtrans<<<256, blk, 0, stream>>>(wv2, wv2t, 256, 256);
  wtrans_sig<<<256, blk, 0, stream>>>(wf2, wf2t);
  wtrans<<<4096, blk, 0, stream>>>(w1, w1t, 512, 2048);
  wtrans_w2<<<2048, blk, 0, stream>>>(w2, w2t);

  const int qkStride = Mc * 256;       // elems between qw and kw buffers

  for (int c = 0; c < nc; ++c) {
    const long long off = (long long)c * Mc * 256;
    const float* f0in = feat0 + off;
    const float* f1in = feat1 + off;
    float* outp = (float*)d_out + off;

    // ---- Block 1 (intra) ----
    cvt_f32_bf16<<<gRows, blk, 0, stream>>>(f0in, featb, Mc * 64);
    gemm_nt<MODE_QKV><<<gQK, blk, 0, stream>>>(featb, 256, 0, wq1t, 256, 0, qw, nullptr, nullptr, 256, qkStride);
    gemm_vt<<<gWin, blk, 0, stream>>>(wv1t, featb, vt);
    scores_softmax<<<gSS, blk, 0, stream>>>(qw, kw, mask, SPb);
    gemm_nt<MODE_PV><<<gWin, blk, 0, stream>>>(SPb, 256, 65536, vt, 256, 65536, Ob, nullptr, nullptr, 256, 0);
    gemm_ln<LN_XCAT0><<<gLN, blk, 0, stream>>>(Ob, 256, wf1t, g1, b1, f0in, nullptr, nullptr, xcat, 256);

    // ---- Block 2 (inter) ----
    cvt_f32_bf16<<<gRows, blk, 0, stream>>>(f1in, featb, Mc * 64);
    gemm_nt<MODE_QKV><<<gBig, blk, 0, stream>>>(xcat, 512, 0, wq2t, 256, 0, qw, nullptr, nullptr, 512, 0);
    gemm_nt<MODE_QKV><<<gBig, blk, 0, stream>>>(featb, 256, 0, wk2t, 256, 0, kw, nullptr, nullptr, 256, 0);
    gemm_vt<<<gWin, blk, 0, stream>>>(wv2t, featb, vt);
    scores_softmax<<<gSS, blk, 0, stream>>>(qw, kw, mask, SPb);
    gemm_nt<MODE_PV><<<gWin, blk, 0, stream>>>(SPb, 256, 65536, vt, 256, 65536, Ob, nullptr, nullptr, 256, 0);
    gemm_ln<LN_XCAT1><<<gLN, blk, 0, stream>>>(Ob, 256, wf2t, g2, b2, nullptr, nullptr, nullptr, xcat, 256);

    // ---- FFN: 2 M-chunks; hbuf spans [0,4S) (featb/qw/kw regions all dead) ----
    for (int mc = 0; mc < 2; ++mc) {
      const u16* xc = xcat + (long long)mc * MF * 512;
      gemm_nt<MODE_FFN1><<<gF1, blk, 0, stream>>>(xc, 512, 0, w1t, 512, 0,
                                                  hbuf, nullptr, nullptr, 512, 2048);
      gemm_ln<LN_OUT><<<gLNF, blk, 0, stream>>>(hbuf, 2048, w2t, fg, fb, nullptr,
                                                xcat + (long long)mc * MF * 512,
                                                outp + (long long)mc * MF * 256, nullptr, 2048);
    }
  }
}